// Round 1
// baseline (16487.508 us; speedup 1.0000x reference)
//
#include <hip/hip_runtime.h>
#include <hip/hip_bf16.h>
#include <stdint.h>

// Problem constants
#define B_SZ   64
#define L_SEQ  512
#define DIN    1024
#define HDIM   1024
#define G4     4096   // 4*H
// out layout: outputs [64*512*1024], h_fin [64*1024], c_fin [64*1024]
#define OUT_HFIN 33554432L
#define OUT_CFIN 33619968L

typedef float  f32x4 __attribute__((ext_vector_type(4)));
typedef short  s16x8 __attribute__((ext_vector_type(8)));
typedef unsigned short u16;

// ---- workspace layout (bytes) ----
// x_bf16  : 33554432 * 2 = 67108864
// Wx_bf16 : 4096*1024*2  =  8388608
// Wh_bf16 : 4096*1024*2  =  8388608
// xproj   : 32768*4096*2 = 268435456
// hbuf    : 2 * 64*1024*2 = 262144   (ping-pong)
// ctr     : 16
#define OFF_XBF   0ULL
#define OFF_WX    67108864ULL
#define OFF_WH    75497472ULL
#define OFF_XPROJ 83886080ULL
#define OFF_HBUF  352321536ULL
#define OFF_CTR   352583680ULL

static __device__ __forceinline__ u16 f2bf(float f) {
    __hip_bfloat16 h = __float2bfloat16(f);
    return *reinterpret_cast<u16*>(&h);
}
static __device__ __forceinline__ float bf2f(u16 u) {
    union { uint32_t i; float f; } v;
    v.i = ((uint32_t)u) << 16;
    return v.f;
}
static __device__ __forceinline__ float fsigmoid(float x) {
    return __builtin_amdgcn_rcpf(1.0f + __expf(-x));
}
static __device__ __forceinline__ float ftanh(float x) {
    // 1 - 2/(1+e^{2x}) : stable at both extremes
    return 1.0f - 2.0f * __builtin_amdgcn_rcpf(1.0f + __expf(2.0f * x));
}

// ============================ prep: fp32 -> bf16 ============================
__global__ void prep_kernel(const float* __restrict__ x, const float* __restrict__ W,
                            u16* __restrict__ xbf, u16* __restrict__ wx,
                            u16* __restrict__ wh, int* __restrict__ ctr) {
    long tid = (long)blockIdx.x * blockDim.x + threadIdx.x;
    long stride = (long)gridDim.x * blockDim.x;
    const long NX4 = 33554432 / 4;
    for (long i = tid; i < NX4; i += stride) {
        float4 v = ((const float4*)x)[i];
        ushort4 o;
        o.x = f2bf(v.x); o.y = f2bf(v.y); o.z = f2bf(v.z); o.w = f2bf(v.w);
        ((ushort4*)xbf)[i] = o;
    }
    const long NW4 = 8388608 / 4;
    for (long i = tid; i < NW4; i += stride) {
        float4 v = ((const float4*)W)[i];
        long f = i * 4;
        long n = f >> 11;        // row of W (2048 wide)
        long c = f & 2047;
        ushort4 o;
        o.x = f2bf(v.x); o.y = f2bf(v.y); o.z = f2bf(v.z); o.w = f2bf(v.w);
        u16* dst = (c < 1024) ? &wh[n * 1024 + c] : &wx[n * 1024 + (c - 1024)];
        *(ushort4*)dst = o;
    }
    if (blockIdx.x == 0 && threadIdx.x < 4) ctr[threadIdx.x] = 0;
}

// ==================== phase 1: x_proj = x @ Wx^T + b (bf16 out) =============
// C[m][n] = sum_k x[m][k]*Wx[n][k]; both operands K-contiguous row-major.
// BM=BN=128, BK=32, 256 threads = 2x2 waves of 64x64.
__global__ __launch_bounds__(256) void xproj_gemm(const u16* __restrict__ xbf,
                                                  const u16* __restrict__ wxbf,
                                                  const float* __restrict__ bias,
                                                  u16* __restrict__ xproj) {
    __shared__ u16 As[128 * 32];
    __shared__ u16 Bs[128 * 32];
    const int tid  = threadIdx.x;
    const int lane = tid & 63;
    const int w    = tid >> 6;
    const int wm   = w >> 1, wn = w & 1;
    const int l15  = lane & 15, quad = lane >> 4;
    const int m0 = blockIdx.y * 128;
    const int n0 = blockIdx.x * 128;

    const int rowA = tid >> 2,          colA = (tid & 3) * 8;          // chunk tid
    const int rowB = (tid + 256) >> 2,  colB = ((tid + 256) & 3) * 8;  // chunk tid+256

    f32x4 acc[4][4];
#pragma unroll
    for (int i = 0; i < 4; ++i)
#pragma unroll
        for (int j = 0; j < 4; ++j) acc[i][j] = 0.0f;

    // prefetch tile 0
    s16x8 a0 = *(const s16x8*)&xbf [(long)(m0 + rowA) * 1024 + colA];
    s16x8 a1 = *(const s16x8*)&xbf [(long)(m0 + rowB) * 1024 + colB];
    s16x8 b0 = *(const s16x8*)&wxbf[(long)(n0 + rowA) * 1024 + colA];
    s16x8 b1 = *(const s16x8*)&wxbf[(long)(n0 + rowB) * 1024 + colB];

    for (int kt = 0; kt < 32; ++kt) {
        *(s16x8*)&As[rowA * 32 + colA] = a0;
        *(s16x8*)&As[rowB * 32 + colB] = a1;
        *(s16x8*)&Bs[rowA * 32 + colA] = b0;
        *(s16x8*)&Bs[rowB * 32 + colB] = b1;
        __syncthreads();
        if (kt < 31) {  // prefetch next tile while computing this one
            const int k0 = (kt + 1) * 32;
            a0 = *(const s16x8*)&xbf [(long)(m0 + rowA) * 1024 + k0 + colA];
            a1 = *(const s16x8*)&xbf [(long)(m0 + rowB) * 1024 + k0 + colB];
            b0 = *(const s16x8*)&wxbf[(long)(n0 + rowA) * 1024 + k0 + colA];
            b1 = *(const s16x8*)&wxbf[(long)(n0 + rowB) * 1024 + k0 + colB];
        }
        s16x8 af[4], bfr[4];
#pragma unroll
        for (int mt = 0; mt < 4; ++mt)
            af[mt] = *(const s16x8*)&As[(wm * 64 + mt * 16 + l15) * 32 + quad * 8];
#pragma unroll
        for (int nt = 0; nt < 4; ++nt)
            bfr[nt] = *(const s16x8*)&Bs[(wn * 64 + nt * 16 + l15) * 32 + quad * 8];
#pragma unroll
        for (int mt = 0; mt < 4; ++mt)
#pragma unroll
            for (int nt = 0; nt < 4; ++nt)
                acc[mt][nt] = __builtin_amdgcn_mfma_f32_16x16x32_bf16(af[mt], bfr[nt], acc[mt][nt], 0, 0, 0);
        __syncthreads();
    }
    // epilogue: + bias, cast bf16, store (D: row = quad*4+reg <-> m, col = l15 <-> n)
#pragma unroll
    for (int nt = 0; nt < 4; ++nt) {
        int n = n0 + wn * 64 + nt * 16 + l15;
        float bv = bias[n];
#pragma unroll
        for (int mt = 0; mt < 4; ++mt) {
            int mbase = m0 + wm * 64 + mt * 16 + quad * 4;
#pragma unroll
            for (int r = 0; r < 4; ++r)
                xproj[(long)(mbase + r) * 4096 + n] = f2bf(acc[mt][nt][r] + bv);
        }
    }
}

// ======================= phase 2: sequential recurrence =====================
// grid = 256 blocks: g = bid&3 (16 batch rows), jc = bid>>2 (16 h-cols).
// wave w (0..3) = gate w (f,i,g,o): computes gates[16b x 16col] for gate w.
// Wh fragments live in VGPRs (128/lane); h staged via LDS each step.
// Per-group 64-block barrier: monotonic counter, release/acquire, agent scope.
__global__ __launch_bounds__(256, 2) void lstm_rec(const u16* __restrict__ whbf,
                                                   const u16* __restrict__ xproj,
                                                   u16* __restrict__ hbuf,
                                                   float* __restrict__ out,
                                                   int* __restrict__ ctr) {
    __shared__ u16  h_s[16 * 1032];        // 16 rows, stride 1032 elems (pad 8)
    __shared__ float gates_s[4][16][16];
    __shared__ float c_s[16][16];

    const int tid  = threadIdx.x;
    const int w    = tid >> 6;
    const int lane = tid & 63;
    const int l15  = lane & 15, quad = lane >> 4;
    const int g    = blockIdx.x & 3;
    const int jc   = blockIdx.x >> 2;
    const int bbase = g * 16;
    int* gctr = &ctr[g];

    // Wh fragments -> registers: wave w's B-rows n = w*1024 + jc*16 + l15
    const long nrow = (long)w * 1024 + jc * 16 + l15;
    s16x8 bfrag[32];
#pragma unroll
    for (int kc = 0; kc < 32; ++kc)
        bfrag[kc] = *(const s16x8*)&whbf[nrow * 1024 + kc * 32 + quad * 8];

    c_s[tid >> 4][tid & 15] = 0.0f;

    for (int t = 0; t < 512; ++t) {
        // prefetch xproj tile for this step (consumed after K-loop)
        float xp[4];
#pragma unroll
        for (int r = 0; r < 4; ++r) {
            long brow = bbase + quad * 4 + r;
            xp[r] = bf2f(xproj[(brow * 512 + t) * 4096 + (long)w * 1024 + jc * 16 + l15]);
        }
        // stage h_{t-1} into LDS (zeros at t=0)
        if (t == 0) {
            s16x8 z = 0;
#pragma unroll
            for (int it = 0; it < 8; ++it) {
                int c = tid + it * 256;
                *(s16x8*)&h_s[(c >> 7) * 1032 + (c & 127) * 8] = z;
            }
        } else {
            const u16* hsrc = hbuf + ((t + 1) & 1) * 65536;  // written at step t-1
#pragma unroll
            for (int it = 0; it < 8; ++it) {
                int c = tid + it * 256;
                int row = c >> 7, o8 = (c & 127) * 8;
                s16x8 v = *(const s16x8*)&hsrc[(long)(bbase + row) * 1024 + o8];
                *(s16x8*)&h_s[row * 1032 + o8] = v;
            }
        }
        __syncthreads();

        // gates tile: A = h (m=batch=l15), B = Wh (n=l15), 4 acc chains over K
        f32x4 ac0 = 0.0f, ac1 = 0.0f, ac2 = 0.0f, ac3 = 0.0f;
#pragma unroll
        for (int kc = 0; kc < 32; kc += 4) {
            s16x8 a;
            a = *(const s16x8*)&h_s[l15 * 1032 + (kc + 0) * 32 + quad * 8];
            ac0 = __builtin_amdgcn_mfma_f32_16x16x32_bf16(a, bfrag[kc + 0], ac0, 0, 0, 0);
            a = *(const s16x8*)&h_s[l15 * 1032 + (kc + 1) * 32 + quad * 8];
            ac1 = __builtin_amdgcn_mfma_f32_16x16x32_bf16(a, bfrag[kc + 1], ac1, 0, 0, 0);
            a = *(const s16x8*)&h_s[l15 * 1032 + (kc + 2) * 32 + quad * 8];
            ac2 = __builtin_amdgcn_mfma_f32_16x16x32_bf16(a, bfrag[kc + 2], ac2, 0, 0, 0);
            a = *(const s16x8*)&h_s[l15 * 1032 + (kc + 3) * 32 + quad * 8];
            ac3 = __builtin_amdgcn_mfma_f32_16x16x32_bf16(a, bfrag[kc + 3], ac3, 0, 0, 0);
        }
        f32x4 gate = (ac0 + ac1) + (ac2 + ac3);
#pragma unroll
        for (int r = 0; r < 4; ++r)
            gates_s[w][quad * 4 + r][l15] = gate[r] + xp[r];  // D row = quad*4+r (batch), col = l15
        __syncthreads();

        // elementwise update: wave 0 handles all 16x16 (b,j) cells
        if (w == 0) {
            u16* hdst = hbuf + (t & 1) * 65536;
#pragma unroll
            for (int r = 0; r < 4; ++r) {
                int row = quad * 4 + r;
                float fv = fsigmoid(gates_s[0][row][l15]);
                float iv = fsigmoid(gates_s[1][row][l15]);
                float gv = ftanh   (gates_s[2][row][l15]);
                float ov = fsigmoid(gates_s[3][row][l15]);
                float c  = fv * c_s[row][l15] + iv * gv;
                c_s[row][l15] = c;
                float h = ov * ftanh(c);
                long bg = bbase + row;
                long j  = jc * 16 + l15;
                out[(bg * 512 + t) * 1024 + j] = h;
                hdst[bg * 1024 + j] = f2bf(h);
                if (t == 511) {
                    out[OUT_HFIN + bg * 1024 + j] = h;
                    out[OUT_CFIN + bg * 1024 + j] = c;
                }
            }
        }

        // per-group 64-block barrier (skip after last step)
        if (t < 511) {
            __threadfence();
            __syncthreads();
            if (tid == 0) {
                __hip_atomic_fetch_add(gctr, 1, __ATOMIC_RELEASE, __HIP_MEMORY_SCOPE_AGENT);
                const int target = 64 * (t + 1);
                while (__hip_atomic_load(gctr, __ATOMIC_ACQUIRE, __HIP_MEMORY_SCOPE_AGENT) < target)
                    __builtin_amdgcn_s_sleep(1);
            }
            __syncthreads();
        }
    }
}

// ================================ launcher =================================
extern "C" void kernel_launch(void* const* d_in, const int* in_sizes, int n_in,
                              void* d_out, int out_size, void* d_ws, size_t ws_size,
                              hipStream_t stream) {
    const float* x    = (const float*)d_in[0];
    const float* W    = (const float*)d_in[1];
    const float* bias = (const float*)d_in[2];
    float* out = (float*)d_out;
    char*  ws  = (char*)d_ws;

    u16* xbf   = (u16*)(ws + OFF_XBF);
    u16* wx    = (u16*)(ws + OFF_WX);
    u16* wh    = (u16*)(ws + OFF_WH);
    u16* xproj = (u16*)(ws + OFF_XPROJ);
    u16* hbuf  = (u16*)(ws + OFF_HBUF);
    int* ctr   = (int*)(ws + OFF_CTR);

    hipLaunchKernelGGL(prep_kernel, dim3(2048), dim3(256), 0, stream, x, W, xbf, wx, wh, ctr);
    hipLaunchKernelGGL(xproj_gemm, dim3(32, 256), dim3(256), 0, stream, xbf, wx, bias, xproj);
    hipLaunchKernelGGL(lstm_rec, dim3(256), dim3(256), 0, stream, wh, xproj, hbuf, out, ctr);
}

// Round 2
// 2781.186 us; speedup vs baseline: 5.9282x; 5.9282x over previous
//
#include <hip/hip_runtime.h>
#include <hip/hip_bf16.h>
#include <stdint.h>

// Problem constants
#define B_SZ   64
#define L_SEQ  512
#define DIN    1024
#define HDIM   1024
#define G4     4096   // 4*H
// out layout: outputs [64*512*1024], h_fin [64*1024], c_fin [64*1024]
#define OUT_HFIN 33554432L
#define OUT_CFIN 33619968L

typedef float  f32x4 __attribute__((ext_vector_type(4)));
typedef short  s16x8 __attribute__((ext_vector_type(8)));
typedef unsigned short u16;
typedef unsigned long long u64;

// ---- workspace layout (bytes) ----
#define OFF_XBF   0ULL
#define OFF_WX    67108864ULL
#define OFF_WH    75497472ULL
#define OFF_XPROJ 83886080ULL
#define OFF_HBUF  352321536ULL   // 2 * 64*1024*2 = 262144 (ping-pong)
#define OFF_CTR   352583680ULL   // 64 ints (4 counters padded 64B apart)

static __device__ __forceinline__ u16 f2bf(float f) {
    __hip_bfloat16 h = __float2bfloat16(f);
    return *reinterpret_cast<u16*>(&h);
}
static __device__ __forceinline__ float bf2f(u16 u) {
    union { uint32_t i; float f; } v;
    v.i = ((uint32_t)u) << 16;
    return v.f;
}
static __device__ __forceinline__ float fsigmoid(float x) {
    return __builtin_amdgcn_rcpf(1.0f + __expf(-x));
}
static __device__ __forceinline__ float ftanh(float x) {
    return 1.0f - 2.0f * __builtin_amdgcn_rcpf(1.0f + __expf(2.0f * x));
}

// ============================ prep: fp32 -> bf16 ============================
__global__ void prep_kernel(const float* __restrict__ x, const float* __restrict__ W,
                            u16* __restrict__ xbf, u16* __restrict__ wx,
                            u16* __restrict__ wh, int* __restrict__ ctr) {
    long tid = (long)blockIdx.x * blockDim.x + threadIdx.x;
    long stride = (long)gridDim.x * blockDim.x;
    const long NX4 = 33554432 / 4;
    for (long i = tid; i < NX4; i += stride) {
        float4 v = ((const float4*)x)[i];
        ushort4 o;
        o.x = f2bf(v.x); o.y = f2bf(v.y); o.z = f2bf(v.z); o.w = f2bf(v.w);
        ((ushort4*)xbf)[i] = o;
    }
    const long NW4 = 8388608 / 4;
    for (long i = tid; i < NW4; i += stride) {
        float4 v = ((const float4*)W)[i];
        long f = i * 4;
        long n = f >> 11;        // row of W (2048 wide)
        long c = f & 2047;
        ushort4 o;
        o.x = f2bf(v.x); o.y = f2bf(v.y); o.z = f2bf(v.z); o.w = f2bf(v.w);
        u16* dst = (c < 1024) ? &wh[n * 1024 + c] : &wx[n * 1024 + (c - 1024)];
        *(ushort4*)dst = o;
    }
    if (blockIdx.x == 0 && threadIdx.x < 64) ctr[threadIdx.x] = 0;
}

// ==================== phase 1: x_proj = x @ Wx^T + b (bf16 out) =============
__global__ __launch_bounds__(256) void xproj_gemm(const u16* __restrict__ xbf,
                                                  const u16* __restrict__ wxbf,
                                                  const float* __restrict__ bias,
                                                  u16* __restrict__ xproj) {
    __shared__ u16 As[128 * 32];
    __shared__ u16 Bs[128 * 32];
    const int tid  = threadIdx.x;
    const int lane = tid & 63;
    const int w    = tid >> 6;
    const int wm   = w >> 1, wn = w & 1;
    const int l15  = lane & 15, quad = lane >> 4;
    const int m0 = blockIdx.y * 128;
    const int n0 = blockIdx.x * 128;

    const int rowA = tid >> 2,          colA = (tid & 3) * 8;
    const int rowB = (tid + 256) >> 2,  colB = ((tid + 256) & 3) * 8;

    f32x4 acc[4][4];
#pragma unroll
    for (int i = 0; i < 4; ++i)
#pragma unroll
        for (int j = 0; j < 4; ++j) acc[i][j] = 0.0f;

    s16x8 a0 = *(const s16x8*)&xbf [(long)(m0 + rowA) * 1024 + colA];
    s16x8 a1 = *(const s16x8*)&xbf [(long)(m0 + rowB) * 1024 + colB];
    s16x8 b0 = *(const s16x8*)&wxbf[(long)(n0 + rowA) * 1024 + colA];
    s16x8 b1 = *(const s16x8*)&wxbf[(long)(n0 + rowB) * 1024 + colB];

    for (int kt = 0; kt < 32; ++kt) {
        *(s16x8*)&As[rowA * 32 + colA] = a0;
        *(s16x8*)&As[rowB * 32 + colB] = a1;
        *(s16x8*)&Bs[rowA * 32 + colA] = b0;
        *(s16x8*)&Bs[rowB * 32 + colB] = b1;
        __syncthreads();
        if (kt < 31) {
            const int k0 = (kt + 1) * 32;
            a0 = *(const s16x8*)&xbf [(long)(m0 + rowA) * 1024 + k0 + colA];
            a1 = *(const s16x8*)&xbf [(long)(m0 + rowB) * 1024 + k0 + colB];
            b0 = *(const s16x8*)&wxbf[(long)(n0 + rowA) * 1024 + k0 + colA];
            b1 = *(const s16x8*)&wxbf[(long)(n0 + rowB) * 1024 + k0 + colB];
        }
        s16x8 af[4], bfr[4];
#pragma unroll
        for (int mt = 0; mt < 4; ++mt)
            af[mt] = *(const s16x8*)&As[(wm * 64 + mt * 16 + l15) * 32 + quad * 8];
#pragma unroll
        for (int nt = 0; nt < 4; ++nt)
            bfr[nt] = *(const s16x8*)&Bs[(wn * 64 + nt * 16 + l15) * 32 + quad * 8];
#pragma unroll
        for (int mt = 0; mt < 4; ++mt)
#pragma unroll
            for (int nt = 0; nt < 4; ++nt)
                acc[mt][nt] = __builtin_amdgcn_mfma_f32_16x16x32_bf16(af[mt], bfr[nt], acc[mt][nt], 0, 0, 0);
        __syncthreads();
    }
#pragma unroll
    for (int nt = 0; nt < 4; ++nt) {
        int n = n0 + wn * 64 + nt * 16 + l15;
        float bv = bias[n];
#pragma unroll
        for (int mt = 0; mt < 4; ++mt) {
            int mbase = m0 + wm * 64 + mt * 16 + quad * 4;
#pragma unroll
            for (int r = 0; r < 4; ++r)
                xproj[(long)(mbase + r) * 4096 + n] = f2bf(acc[mt][nt][r] + bv);
        }
    }
}

// ======================= phase 2: sequential recurrence =====================
// 256 blocks: g = bid&3 (16 batch rows), jc = bid>>2 (16 h-cols).
// Cross-block h + barrier counter: RELAXED agent-scope atomics only (single
// coherent global_load/store, NO fence instructions -> no L2 wb/inv storm).
// Ordering: wave0 h-stores -> s_waitcnt vmcnt(0) -> counter add; readers poll
// counter then issue coherent h loads (data reached MALL before the flag).
__global__ __launch_bounds__(256, 2) void lstm_rec(const u16* __restrict__ whbf,
                                                   const u16* __restrict__ xproj,
                                                   u16* __restrict__ hbuf,
                                                   float* __restrict__ out,
                                                   int* __restrict__ ctr) {
    __shared__ u16  h_s[16 * 1032];        // 16 rows, stride 1032 elems (pad 8)
    __shared__ float gates_s[4][16][16];
    __shared__ float c_s[16][16];
    __shared__ u16  ho[16][16];            // h transpose staging (wave 0 only)

    const int tid  = threadIdx.x;
    const int w    = tid >> 6;
    const int lane = tid & 63;
    const int l15  = lane & 15, quad = lane >> 4;
    const int g    = blockIdx.x & 3;
    const int jc   = blockIdx.x >> 2;
    const int bbase = g * 16;
    int* gctr = &ctr[g * 16];              // 64B-padded counters

    // Wh fragments -> registers: wave w's B-rows n = w*1024 + jc*16 + l15
    const long nrow = (long)w * 1024 + jc * 16 + l15;
    s16x8 bfrag[32];
#pragma unroll
    for (int kc = 0; kc < 32; ++kc)
        bfrag[kc] = *(const s16x8*)&whbf[nrow * 1024 + kc * 32 + quad * 8];

    c_s[tid >> 4][tid & 15] = 0.0f;

    u64* hb64[2] = { (u64*)hbuf, (u64*)(hbuf + 65536) };

    // xp prefetch for t=0
    const u16* xpbase = xproj + (long)w * 1024 + jc * 16 + l15;
    float xp[4];
#pragma unroll
    for (int r = 0; r < 4; ++r)
        xp[r] = bf2f(xpbase[(long)(bbase + quad * 4 + r) * 512 * 4096]);

    for (int t = 0; t < 512; ++t) {
        // ---- stage h_{t-1} into LDS ----
        if (t == 0) {
            u64 z = 0;
#pragma unroll
            for (int it = 0; it < 16; ++it) {
                int c = tid + it * 256;            // 0..4095 u64 slots
                int row = c >> 8, cw = c & 255;
                *(u64*)&h_s[row * 1032 + cw * 4] = z;
            }
        } else {
            const u64* hsrc = hb64[(t + 1) & 1];   // buffer written at t-1
            u64 tmp[16];
#pragma unroll
            for (int it = 0; it < 16; ++it) {
                int c = tid + it * 256;
                int row = c >> 8, cw = c & 255;
                tmp[it] = __hip_atomic_load(&hsrc[(bbase + row) * 256 + cw],
                                            __ATOMIC_RELAXED, __HIP_MEMORY_SCOPE_AGENT);
            }
#pragma unroll
            for (int it = 0; it < 16; ++it) {
                int c = tid + it * 256;
                int row = c >> 8, cw = c & 255;
                *(u64*)&h_s[row * 1032 + cw * 4] = tmp[it];
            }
        }
        __syncthreads();

        // ---- gates tile: A = h (m=batch), B = Wh, K=1024 ----
        f32x4 ac0 = 0.0f, ac1 = 0.0f, ac2 = 0.0f, ac3 = 0.0f;
#pragma unroll
        for (int kc = 0; kc < 32; kc += 4) {
            s16x8 a;
            a = *(const s16x8*)&h_s[l15 * 1032 + (kc + 0) * 32 + quad * 8];
            ac0 = __builtin_amdgcn_mfma_f32_16x16x32_bf16(a, bfrag[kc + 0], ac0, 0, 0, 0);
            a = *(const s16x8*)&h_s[l15 * 1032 + (kc + 1) * 32 + quad * 8];
            ac1 = __builtin_amdgcn_mfma_f32_16x16x32_bf16(a, bfrag[kc + 1], ac1, 0, 0, 0);
            a = *(const s16x8*)&h_s[l15 * 1032 + (kc + 2) * 32 + quad * 8];
            ac2 = __builtin_amdgcn_mfma_f32_16x16x32_bf16(a, bfrag[kc + 2], ac2, 0, 0, 0);
            a = *(const s16x8*)&h_s[l15 * 1032 + (kc + 3) * 32 + quad * 8];
            ac3 = __builtin_amdgcn_mfma_f32_16x16x32_bf16(a, bfrag[kc + 3], ac3, 0, 0, 0);
        }
        f32x4 gate = (ac0 + ac1) + (ac2 + ac3);
#pragma unroll
        for (int r = 0; r < 4; ++r)
            gates_s[w][quad * 4 + r][l15] = gate[r] + xp[r];
        __syncthreads();

        // ---- elementwise update (wave 0) + coherent h store ----
        if (w == 0) {
#pragma unroll
            for (int r = 0; r < 4; ++r) {
                int row = quad * 4 + r;
                float fv = fsigmoid(gates_s[0][row][l15]);
                float iv = fsigmoid(gates_s[1][row][l15]);
                float gv = ftanh   (gates_s[2][row][l15]);
                float ov = fsigmoid(gates_s[3][row][l15]);
                float c  = fv * c_s[row][l15] + iv * gv;
                c_s[row][l15] = c;
                float h = ov * ftanh(c);
                long bg = bbase + row;
                long j  = jc * 16 + l15;
                out[(bg * 512 + t) * 1024 + j] = h;
                ho[row][l15] = f2bf(h);
                if (t == 511) {
                    out[OUT_HFIN + bg * 1024 + j] = h;
                    out[OUT_CFIN + bg * 1024 + j] = c;
                }
            }
            if (t < 511) {
                // transpose via LDS (same-wave DS ops are in-order) -> 8B stores
                int orow = lane >> 2, oc4 = (lane & 3) * 4;
                u64 v = *(u64*)&ho[orow][oc4];
                __hip_atomic_store(&hb64[t & 1][((long)(bbase + orow) * 1024 + jc * 16 + oc4) >> 2],
                                   v, __ATOMIC_RELAXED, __HIP_MEMORY_SCOPE_AGENT);
            }
        }

        // ---- prefetch next xp (plain cached loads; latency hides under barrier) ----
        if (t + 1 < 512) {
#pragma unroll
            for (int r = 0; r < 4; ++r)
                xp[r] = bf2f(xpbase[((long)(bbase + quad * 4 + r) * 512 + (t + 1)) * 4096]);
        }

        // ---- per-group 64-block barrier ----
        if (t < 511) {
            if (tid == 0) {
                __asm__ volatile("s_waitcnt vmcnt(0)" ::: "memory");   // h stores acked
                __hip_atomic_fetch_add(gctr, 1, __ATOMIC_RELAXED, __HIP_MEMORY_SCOPE_AGENT);
                const int target = 64 * (t + 1);
                while (__hip_atomic_load(gctr, __ATOMIC_RELAXED, __HIP_MEMORY_SCOPE_AGENT) < target)
                    __builtin_amdgcn_s_sleep(2);
            }
            __syncthreads();
        }
    }
}

// ================================ launcher =================================
extern "C" void kernel_launch(void* const* d_in, const int* in_sizes, int n_in,
                              void* d_out, int out_size, void* d_ws, size_t ws_size,
                              hipStream_t stream) {
    const float* x    = (const float*)d_in[0];
    const float* W    = (const float*)d_in[1];
    const float* bias = (const float*)d_in[2];
    float* out = (float*)d_out;
    char*  ws  = (char*)d_ws;

    u16* xbf   = (u16*)(ws + OFF_XBF);
    u16* wx    = (u16*)(ws + OFF_WX);
    u16* wh    = (u16*)(ws + OFF_WH);
    u16* xproj = (u16*)(ws + OFF_XPROJ);
    u16* hbuf  = (u16*)(ws + OFF_HBUF);
    int* ctr   = (int*)(ws + OFF_CTR);

    hipLaunchKernelGGL(prep_kernel, dim3(2048), dim3(256), 0, stream, x, W, xbf, wx, wh, ctr);
    hipLaunchKernelGGL(xproj_gemm, dim3(32, 256), dim3(256), 0, stream, xbf, wx, bias, xproj);
    hipLaunchKernelGGL(lstm_rec, dim3(256), dim3(256), 0, stream, wh, xproj, hbuf, out, ctr);
}

// Round 3
// 2186.300 us; speedup vs baseline: 7.5413x; 1.2721x over previous
//
#include <hip/hip_runtime.h>
#include <hip/hip_bf16.h>
#include <stdint.h>

// Problem constants
#define B_SZ   64
#define L_SEQ  512
#define DIN    1024
#define HDIM   1024
#define G4     4096   // 4*H
// out layout: outputs [64*512*1024], h_fin [64*1024], c_fin [64*1024]
#define OUT_HFIN 33554432L
#define OUT_CFIN 33619968L

typedef float  f32x4 __attribute__((ext_vector_type(4)));
typedef short  s16x8 __attribute__((ext_vector_type(8)));
typedef unsigned short u16;
typedef unsigned long long u64;

// ---- workspace layout (bytes) ----
#define OFF_XBF   0ULL
#define OFF_WX    67108864ULL
#define OFF_WH    75497472ULL
#define OFF_XPROJ 83886080ULL
#define OFF_HBUF  352321536ULL   // 2 * 64*1024*2 = 262144 (ping-pong)
#define OFF_FLG   352583680ULL   // 4 groups * 64 int flags = 1KB

static __device__ __forceinline__ u16 f2bf(float f) {
    __hip_bfloat16 h = __float2bfloat16(f);
    return *reinterpret_cast<u16*>(&h);
}
static __device__ __forceinline__ float bf2f(u16 u) {
    union { uint32_t i; float f; } v;
    v.i = ((uint32_t)u) << 16;
    return v.f;
}
static __device__ __forceinline__ float fsigmoid(float x) {
    return __builtin_amdgcn_rcpf(1.0f + __expf(-x));
}
static __device__ __forceinline__ float ftanh(float x) {
    return 1.0f - 2.0f * __builtin_amdgcn_rcpf(1.0f + __expf(2.0f * x));
}

// ============================ prep: fp32 -> bf16 ============================
__global__ void prep_kernel(const float* __restrict__ x, const float* __restrict__ W,
                            u16* __restrict__ xbf, u16* __restrict__ wx,
                            u16* __restrict__ wh, int* __restrict__ flg) {
    long tid = (long)blockIdx.x * blockDim.x + threadIdx.x;
    long stride = (long)gridDim.x * blockDim.x;
    const long NX4 = 33554432 / 4;
    for (long i = tid; i < NX4; i += stride) {
        float4 v = ((const float4*)x)[i];
        ushort4 o;
        o.x = f2bf(v.x); o.y = f2bf(v.y); o.z = f2bf(v.z); o.w = f2bf(v.w);
        ((ushort4*)xbf)[i] = o;
    }
    const long NW4 = 8388608 / 4;
    for (long i = tid; i < NW4; i += stride) {
        float4 v = ((const float4*)W)[i];
        long f = i * 4;
        long n = f >> 11;        // row of W (2048 wide)
        long c = f & 2047;
        ushort4 o;
        o.x = f2bf(v.x); o.y = f2bf(v.y); o.z = f2bf(v.z); o.w = f2bf(v.w);
        u16* dst = (c < 1024) ? &wh[n * 1024 + c] : &wx[n * 1024 + (c - 1024)];
        *(ushort4*)dst = o;
    }
    if (blockIdx.x == 0 && threadIdx.x < 256) flg[threadIdx.x] = 0;
}

// ==================== phase 1: x_proj = x @ Wx^T + b (bf16 out) =============
__global__ __launch_bounds__(256) void xproj_gemm(const u16* __restrict__ xbf,
                                                  const u16* __restrict__ wxbf,
                                                  const float* __restrict__ bias,
                                                  u16* __restrict__ xproj) {
    __shared__ u16 As[128 * 32];
    __shared__ u16 Bs[128 * 32];
    const int tid  = threadIdx.x;
    const int lane = tid & 63;
    const int w    = tid >> 6;
    const int wm   = w >> 1, wn = w & 1;
    const int l15  = lane & 15, quad = lane >> 4;
    const int m0 = blockIdx.y * 128;
    const int n0 = blockIdx.x * 128;

    const int rowA = tid >> 2,          colA = (tid & 3) * 8;
    const int rowB = (tid + 256) >> 2,  colB = ((tid + 256) & 3) * 8;

    f32x4 acc[4][4];
#pragma unroll
    for (int i = 0; i < 4; ++i)
#pragma unroll
        for (int j = 0; j < 4; ++j) acc[i][j] = 0.0f;

    s16x8 a0 = *(const s16x8*)&xbf [(long)(m0 + rowA) * 1024 + colA];
    s16x8 a1 = *(const s16x8*)&xbf [(long)(m0 + rowB) * 1024 + colB];
    s16x8 b0 = *(const s16x8*)&wxbf[(long)(n0 + rowA) * 1024 + colA];
    s16x8 b1 = *(const s16x8*)&wxbf[(long)(n0 + rowB) * 1024 + colB];

    for (int kt = 0; kt < 32; ++kt) {
        *(s16x8*)&As[rowA * 32 + colA] = a0;
        *(s16x8*)&As[rowB * 32 + colB] = a1;
        *(s16x8*)&Bs[rowA * 32 + colA] = b0;
        *(s16x8*)&Bs[rowB * 32 + colB] = b1;
        __syncthreads();
        if (kt < 31) {
            const int k0 = (kt + 1) * 32;
            a0 = *(const s16x8*)&xbf [(long)(m0 + rowA) * 1024 + k0 + colA];
            a1 = *(const s16x8*)&xbf [(long)(m0 + rowB) * 1024 + k0 + colB];
            b0 = *(const s16x8*)&wxbf[(long)(n0 + rowA) * 1024 + k0 + colA];
            b1 = *(const s16x8*)&wxbf[(long)(n0 + rowB) * 1024 + k0 + colB];
        }
        s16x8 af[4], bfr[4];
#pragma unroll
        for (int mt = 0; mt < 4; ++mt)
            af[mt] = *(const s16x8*)&As[(wm * 64 + mt * 16 + l15) * 32 + quad * 8];
#pragma unroll
        for (int nt = 0; nt < 4; ++nt)
            bfr[nt] = *(const s16x8*)&Bs[(wn * 64 + nt * 16 + l15) * 32 + quad * 8];
#pragma unroll
        for (int mt = 0; mt < 4; ++mt)
#pragma unroll
            for (int nt = 0; nt < 4; ++nt)
                acc[mt][nt] = __builtin_amdgcn_mfma_f32_16x16x32_bf16(af[mt], bfr[nt], acc[mt][nt], 0, 0, 0);
        __syncthreads();
    }
#pragma unroll
    for (int nt = 0; nt < 4; ++nt) {
        int n = n0 + wn * 64 + nt * 16 + l15;
        float bv = bias[n];
#pragma unroll
        for (int mt = 0; mt < 4; ++mt) {
            int mbase = m0 + wm * 64 + mt * 16 + quad * 4;
#pragma unroll
            for (int r = 0; r < 4; ++r)
                xproj[(long)(mbase + r) * 4096 + n] = f2bf(acc[mt][nt][r] + bv);
        }
    }
}

// ======================= phase 2: sequential recurrence =====================
// 256 blocks: g = bid&3 (16 batch rows), jc = bid>>2 (16 h-cols).
// Wave w covers K-slice [256w, 256w+256) for ALL 4 gates (4x less LDS read
// than gate-split); partial gate sums reduced through LDS.
// Sync: per-block flag store (no RMW) after vmcnt-drained h packet stores;
// consumers poll 64 flags (1 coalesced load/lane + ballot).
__global__ __launch_bounds__(256, 1) void lstm_rec(const u16* __restrict__ whbf,
                                                   const u16* __restrict__ xproj,
                                                   u16* __restrict__ hbuf,
                                                   float* __restrict__ out,
                                                   int* __restrict__ flg) {
    __shared__ u16   h_s[16 * 1032];          // 16 rows, stride 1032 (pad 8)
    __shared__ float part[4][16][16][4];      // [gate][row][col][wave]
    __shared__ u16   how[4][4][16];           // [wave][rowInWave][col]

    const int tid  = threadIdx.x;
    const int w    = tid >> 6;
    const int lane = tid & 63;
    const int l15  = lane & 15, quad = lane >> 4;
    const int g    = blockIdx.x & 3;
    const int jc   = blockIdx.x >> 2;
    const int bbase = g * 16;
    const int crow = 4 * w + (lane >> 4);     // elementwise cell row (0..15)
    const int ccol = l15;                     // elementwise cell col (0..15)
    int* fl = flg + g * 64;

    // Wh fragments: wave w holds K-slice [w*256, w*256+256) for all 4 gates.
    s16x8 bfrag[4][8];
#pragma unroll
    for (int gate = 0; gate < 4; ++gate) {
        const long nrow = (long)gate * 1024 + jc * 16 + l15;
#pragma unroll
        for (int kc = 0; kc < 8; ++kc)
            bfrag[gate][kc] = *(const s16x8*)&whbf[nrow * 1024 + w * 256 + kc * 32 + quad * 8];
    }

    float c_reg = 0.0f;
    u64* hb64[2] = { (u64*)hbuf, (u64*)(hbuf + 65536) };

    // xp prefetch for t=0: per-lane, its cell, 4 gates
    const u16* xpcell = xproj + (long)(bbase + crow) * 512 * 4096 + jc * 16 + ccol;
    float xp[4];
#pragma unroll
    for (int gate = 0; gate < 4; ++gate)
        xp[gate] = bf2f(xpcell[(long)gate * 1024]);

    for (int t = 0; t < 512; ++t) {
        // ---- acquire h_{t-1} ----
        if (t == 0) {
            u64 z = 0;
#pragma unroll
            for (int it = 0; it < 16; ++it) {
                int s = tid + it * 256;
                *(u64*)&h_s[(s >> 8) * 1032 + (s & 255) * 4] = z;
            }
        } else {
            // poll flags: lane j watches producer block jc=j of this group
            int v = __hip_atomic_load(&fl[lane], __ATOMIC_RELAXED, __HIP_MEMORY_SCOPE_AGENT);
            while (__ballot(v < t) != 0ULL) {
                __builtin_amdgcn_s_sleep(1);
                v = __hip_atomic_load(&fl[lane], __ATOMIC_RELAXED, __HIP_MEMORY_SCOPE_AGENT);
            }
            const u64* hsrc = hb64[(t + 1) & 1];
            u64 tmp[16];
#pragma unroll
            for (int it = 0; it < 16; ++it) {
                int s = tid + it * 256;
                tmp[it] = __hip_atomic_load(&hsrc[(bbase + (s >> 8)) * 256 + (s & 255)],
                                            __ATOMIC_RELAXED, __HIP_MEMORY_SCOPE_AGENT);
            }
#pragma unroll
            for (int it = 0; it < 16; ++it) {
                int s = tid + it * 256;
                *(u64*)&h_s[(s >> 8) * 1032 + (s & 255) * 4] = tmp[it];
            }
        }
        __syncthreads();   // (A) h_s ready

        // ---- MFMA: K-slice per wave, 4 gate accumulators ----
        f32x4 acc[4];
#pragma unroll
        for (int gate = 0; gate < 4; ++gate) acc[gate] = 0.0f;
#pragma unroll
        for (int kc = 0; kc < 8; ++kc) {
            s16x8 a = *(const s16x8*)&h_s[l15 * 1032 + w * 256 + kc * 32 + quad * 8];
            acc[0] = __builtin_amdgcn_mfma_f32_16x16x32_bf16(a, bfrag[0][kc], acc[0], 0, 0, 0);
            acc[1] = __builtin_amdgcn_mfma_f32_16x16x32_bf16(a, bfrag[1][kc], acc[1], 0, 0, 0);
            acc[2] = __builtin_amdgcn_mfma_f32_16x16x32_bf16(a, bfrag[2][kc], acc[2], 0, 0, 0);
            acc[3] = __builtin_amdgcn_mfma_f32_16x16x32_bf16(a, bfrag[3][kc], acc[3], 0, 0, 0);
        }
        // partial sums to LDS: D row = quad*4+r, col = l15
#pragma unroll
        for (int gate = 0; gate < 4; ++gate)
#pragma unroll
            for (int r = 0; r < 4; ++r)
                part[gate][quad * 4 + r][l15][w] = acc[gate][r];
        __syncthreads();   // (B) partials ready

        // ---- elementwise: each lane owns one (crow, ccol) cell ----
        float gv[4];
#pragma unroll
        for (int gate = 0; gate < 4; ++gate) {
            f32x4 p = *(const f32x4*)&part[gate][crow][ccol][0];
            gv[gate] = ((p[0] + p[1]) + (p[2] + p[3])) + xp[gate];
        }
        float fv = fsigmoid(gv[0]);
        float iv = fsigmoid(gv[1]);
        float gg = ftanh   (gv[2]);
        float ov = fsigmoid(gv[3]);
        c_reg = fv * c_reg + iv * gg;
        float h = ov * ftanh(c_reg);

        long bg = bbase + crow;
        long j  = jc * 16 + ccol;
        out[(bg * 512 + t) * 1024 + j] = h;
        how[w][lane >> 4][ccol] = f2bf(h);
        if (t == 511) {
            out[OUT_HFIN + bg * 1024 + j] = h;
            out[OUT_CFIN + bg * 1024 + j] = c_reg;
        }

        if (t < 511) {
            // h packets: wave w, lanes 0..15 store 1 u64 (4 cols) each
            if (lane < 16) {
                int prow = 4 * w + (lane >> 2);
                int c4   = (lane & 3) * 4;
                u64 v = *(const u64*)&how[w][lane >> 2][c4];
                __hip_atomic_store(&hb64[t & 1][((long)(bbase + prow) * 1024 + jc * 16 + c4) >> 2],
                                   v, __ATOMIC_RELAXED, __HIP_MEMORY_SCOPE_AGENT);
            }
            __asm__ volatile("s_waitcnt vmcnt(0)" ::: "memory");  // h (+out) stores acked
            __syncthreads();   // (C) all waves drained
            if (tid == 0)
                __hip_atomic_store(&fl[jc], t + 1, __ATOMIC_RELAXED, __HIP_MEMORY_SCOPE_AGENT);
            // xp prefetch for t+1 (after flag: off the critical path)
#pragma unroll
            for (int gate = 0; gate < 4; ++gate)
                xp[gate] = bf2f(xpcell[((long)t + 1) * 4096 + (long)gate * 1024]);
        }
    }
}

// ================================ launcher =================================
extern "C" void kernel_launch(void* const* d_in, const int* in_sizes, int n_in,
                              void* d_out, int out_size, void* d_ws, size_t ws_size,
                              hipStream_t stream) {
    const float* x    = (const float*)d_in[0];
    const float* W    = (const float*)d_in[1];
    const float* bias = (const float*)d_in[2];
    float* out = (float*)d_out;
    char*  ws  = (char*)d_ws;

    u16* xbf   = (u16*)(ws + OFF_XBF);
    u16* wx    = (u16*)(ws + OFF_WX);
    u16* wh    = (u16*)(ws + OFF_WH);
    u16* xproj = (u16*)(ws + OFF_XPROJ);
    u16* hbuf  = (u16*)(ws + OFF_HBUF);
    int* flg   = (int*)(ws + OFF_FLG);

    hipLaunchKernelGGL(prep_kernel, dim3(2048), dim3(256), 0, stream, x, W, xbf, wx, wh, flg);
    hipLaunchKernelGGL(xproj_gemm, dim3(32, 256), dim3(256), 0, stream, xbf, wx, bias, xproj);
    hipLaunchKernelGGL(lstm_rec, dim3(256), dim3(256), 0, stream, wh, xproj, hbuf, out, flg);
}